// Round 18
// baseline (178.759 us; speedup 1.0000x reference)
//
#include <hip/hip_runtime.h>
#include <math.h>

#define C 256
#define S 4096
#define NH 8
#define NSGM 32       // 128-s groups per bn = Mp partial groups
#define NSTRIP 64     // 64-s strips per bn = LP/ZP granularity (32 sg x 2)
#define EPS 1e-5f
#define SCALE 0.17677669529663687f   // 1/sqrt(32)

#define TSTR 136      // tile row stride (u16): 272 B rows, 16B-aligned
#define PTSTR 136     // ptT row stride (u16)

// workspace layout (float offsets)
#define OFF_GWP 0                  // 64*256*4 uints = 65536
#define OFF_G   65536              // 512
#define OFF_BC  66048              // 512
#define OFF_LP  66560              // 64*8*64 = 32768
#define OFF_ZP  99328              // 32768
#define OFF_WEI 132096             // 64*8*256 = 131072
#define OFF_MP  263168             // 32*64*256*8 = 4194304

typedef __attribute__((ext_vector_type(8))) short short8;
typedef __attribute__((ext_vector_type(4))) float f32x4;
typedef __attribute__((ext_vector_type(4))) float nfloat4;   // native clang vector (nt-load ok)

__device__ __forceinline__ float bf_lo(unsigned int u) {
    return __builtin_bit_cast(float, u << 16);
}
__device__ __forceinline__ float bf_hi(unsigned int u) {
    return __builtin_bit_cast(float, u & 0xffff0000u);
}
__device__ __forceinline__ unsigned int bf_pack(float a, float b) {
    unsigned int ua = (__builtin_bit_cast(unsigned int, a) + 0x8000u) >> 16;
    unsigned int ub = (__builtin_bit_cast(unsigned int, b) + 0x8000u) & 0xffff0000u;
    return ua | ub;
}
__device__ __forceinline__ float bf_round(float a) {
    unsigned int u = (__builtin_bit_cast(unsigned int, a) + 0x8000u) & 0xffff0000u;
    return __builtin_bit_cast(float, u);
}

// ---------------------------------------------------------------------------
// K1: LN(mask_tokens) -> q -> fold q into Wk. gw packed bf16 pairs [bn][c][4u].
// ---------------------------------------------------------------------------
__global__ __launch_bounds__(256) void k1_prep(
    const float* __restrict__ mt, const float* __restrict__ ln_t_w, const float* __restrict__ ln_t_b,
    const float* __restrict__ ln_p_w, const float* __restrict__ ln_p_b,
    const float* __restrict__ Wq, const float* __restrict__ bq,
    const float* __restrict__ Wk, const float* __restrict__ bk,
    unsigned int* __restrict__ gwp, float* __restrict__ Gv, float* __restrict__ Bc)
{
    int bn  = blockIdx.x;
    int tid = threadIdx.x;
    int wid = tid >> 6, lane = tid & 63;
    __shared__ float nt[C];
    __shared__ float qv[C];
    __shared__ float wks[NH][C];
    __shared__ float red[8];

    float x  = mt[bn * C + tid];
    float s1 = x, s2 = x * x;
    #pragma unroll
    for (int off = 32; off; off >>= 1) {
        s1 += __shfl_xor(s1, off);
        s2 += __shfl_xor(s2, off);
    }
    if (lane == 0) { red[wid] = s1; red[4 + wid] = s2; }
    __syncthreads();
    float mu   = (red[0] + red[1] + red[2] + red[3]) * (1.0f / C);
    float msq  = (red[4] + red[5] + red[6] + red[7]) * (1.0f / C);
    float rstd = rsqrtf(msq - mu * mu + EPS);
    nt[tid] = (x - mu) * rstd * ln_t_w[tid] + ln_t_b[tid];
    __syncthreads();

    {   // q[j=tid] = nt . Wq[j,:] + bq[j]
        float acc = bq[tid];
        const float* wrow = Wq + (size_t)tid * C;
        #pragma unroll 8
        for (int c = 0; c < C; ++c) acc += nt[c] * wrow[c];
        qv[tid] = acc;
    }
    __syncthreads();

    int c = tid;
    #pragma unroll
    for (int h = 0; h < NH; ++h) {
        float a = 0.f;
        #pragma unroll 4
        for (int d = 0; d < 32; ++d) a += qv[h * 32 + d] * Wk[(size_t)(h * 32 + d) * C + c];
        wks[h][c] = a * SCALE;
    }
    __syncthreads();

    for (int i = tid; i < C * 4; i += 256) {
        int cc = i >> 2, pr = i & 3;
        float g0 = ln_p_w[cc] * wks[pr * 2][cc];
        float g1 = ln_p_w[cc] * wks[pr * 2 + 1][cc];
        gwp[(size_t)bn * C * 4 + i] = bf_pack(g0, g1);
    }

    {
        int h = tid >> 5, l32 = tid & 31;
        float g = 0.f, bs = 0.f;
        #pragma unroll
        for (int cc = l32; cc < C; cc += 32) {
            float w = wks[h][cc];
            g  += bf_round(ln_p_w[cc] * w);   // match kfused's unpacked value
            bs += ln_p_b[cc] * w;
        }
        float qb = qv[h * 32 + l32] * bk[h * 32 + l32];
        #pragma unroll
        for (int off = 16; off; off >>= 1) {
            g  += __shfl_xor(g, off);
            bs += __shfl_xor(bs, off);
            qb += __shfl_xor(qb, off);
        }
        if (l32 == 0) {
            Gv[bn * NH + h] = g;
            Bc[bn * NH + h] = bs + qb * SCALE;
        }
    }
}

// ---------------------------------------------------------------------------
// KFUSED v7 (512B DRAM runs): grid 2048 = 64 bn x 32 sg(128 s); 4 waves;
// 1 blk/CU (100 KB LDS). Per c-row the lane batch issues TWO ADJACENT 256B
// segments back-to-back (512B contiguous DRAM runs). 32 nt-loads in flight
// per lane (launch_bounds(256,1) -> ~230 VGPR, no spill budget issue).
// Phase1: stats+tile(bf16). Combine(2 waves): softmax m=0 -> ptT + LP/ZP.
// Phase2: MFMA PV (K=128, 4 MFMA/tile) from LDS -> Mp direct.
// ---------------------------------------------------------------------------
__global__ __launch_bounds__(256, 1) void kfused(
    const float* __restrict__ pe, const unsigned int* __restrict__ gwp,
    const float* __restrict__ Gv, const float* __restrict__ Bc,
    float* __restrict__ LP, float* __restrict__ ZP, float* __restrict__ Mp)
{
    int blk = blockIdx.x;                     // 2048
    int swz = (blk & 7) * 256 + (blk >> 3);   // XCD-contiguous chunks
    int bn  = swz >> 5;
    int sg  = swz & 31;
    int tid = threadIdx.x;
    int w = tid >> 6, lane = tid & 63;
    int cg = lane >> 4, l16 = lane & 15;
    int b = bn >> 3, n = bn & 7;
    const float* xb = pe + ((size_t)(n * 8 + b)) * C * S;
    int s0 = sg * 128;

    __shared__ unsigned short tile[C * TSTR];   // 69632 B  [c][s0..127] bf16
    __shared__ unsigned short ptT[16 * PTSTR];  // 4352 B   [h][s] bf16 (rows 8-15 zero)
    __shared__ float pbuf[4][128][11];          // 22528 B  (stride 11: conflict-free)
    __shared__ uint4 gwt[C];                    // 4096 B

    {
        const uint4* src = reinterpret_cast<const uint4*>(gwp + (size_t)bn * C * 4);
        gwt[tid] = src[tid];
        for (int i = tid; i < 8 * PTSTR; i += 256) ptT[8 * PTSTR + i] = 0;
    }
    __syncthreads();

    // ---- phase 1 ----
    {
        const float* xq = xb + (size_t)(w * 64 + cg) * S + s0 + l16 * 4;
        nfloat4 x0a[8], x1a[8], x0b[8], x1b[8];
        #pragma unroll
        for (int q = 0; q < 8; ++q) {
            const float* p = xq + (size_t)(4 * q) * S;
            x0a[q] = __builtin_nontemporal_load(reinterpret_cast<const nfloat4*>(p));
            x1a[q] = __builtin_nontemporal_load(reinterpret_cast<const nfloat4*>(p + 64));
        }
        #pragma unroll
        for (int q = 0; q < 8; ++q) {
            const float* p = xq + (size_t)(4 * (q + 8)) * S;
            x0b[q] = __builtin_nontemporal_load(reinterpret_cast<const nfloat4*>(p));
            x1b[q] = __builtin_nontemporal_load(reinterpret_cast<const nfloat4*>(p + 64));
        }

        float sum0[4] = {0,0,0,0}, sq0[4] = {0,0,0,0};
        float sum1[4] = {0,0,0,0}, sq1[4] = {0,0,0,0};
        float A0[4][NH], A1[4][NH];
        #pragma unroll
        for (int e = 0; e < 4; ++e)
            #pragma unroll
            for (int h = 0; h < NH; ++h) { A0[e][h] = 0.f; A1[e][h] = 0.f; }

        #define PROC(X0, X1, QB)                                                     \
        {                                                                            \
            _Pragma("unroll")                                                        \
            for (int q = 0; q < 8; ++q) {                                            \
                int cc = w * 64 + 4 * (q + QB) + cg;                                 \
                uint2 pk0, pk1;                                                      \
                pk0.x = bf_pack(X0[q].x, X0[q].y);                                   \
                pk0.y = bf_pack(X0[q].z, X0[q].w);                                   \
                pk1.x = bf_pack(X1[q].x, X1[q].y);                                   \
                pk1.y = bf_pack(X1[q].z, X1[q].w);                                   \
                *reinterpret_cast<uint2*>(&tile[cc * TSTR + l16 * 4]) = pk0;         \
                *reinterpret_cast<uint2*>(&tile[cc * TSTR + 64 + l16 * 4]) = pk1;    \
                uint4 g = gwt[cc];                                                   \
                float ge[8] = {bf_lo(g.x), bf_hi(g.x), bf_lo(g.y), bf_hi(g.y),       \
                               bf_lo(g.z), bf_hi(g.z), bf_lo(g.w), bf_hi(g.w)};     \
                float xe0[4] = {X0[q].x, X0[q].y, X0[q].z, X0[q].w};                 \
                float xe1[4] = {X1[q].x, X1[q].y, X1[q].z, X1[q].w};                 \
                _Pragma("unroll")                                                    \
                for (int e = 0; e < 4; ++e) {                                        \
                    float xx0 = xe0[e], xx1 = xe1[e];                                \
                    sum0[e] += xx0; sq0[e] += xx0 * xx0;                             \
                    sum1[e] += xx1; sq1[e] += xx1 * xx1;                             \
                    _Pragma("unroll")                                                \
                    for (int h = 0; h < NH; ++h) {                                   \
                        A0[e][h] += ge[h] * xx0;                                     \
                        A1[e][h] += ge[h] * xx1;                                     \
                    }                                                                \
                }                                                                    \
            }                                                                        \
        }
        PROC(x0a, x1a, 0)
        PROC(x0b, x1b, 8)
        #undef PROC

        // cg-combine (lanes sharing l16 across cg hold disjoint c-subsets)
        #pragma unroll
        for (int e = 0; e < 4; ++e) {
            sum0[e] += __shfl_xor(sum0[e], 16); sum0[e] += __shfl_xor(sum0[e], 32);
            sq0[e]  += __shfl_xor(sq0[e],  16); sq0[e]  += __shfl_xor(sq0[e],  32);
            sum1[e] += __shfl_xor(sum1[e], 16); sum1[e] += __shfl_xor(sum1[e], 32);
            sq1[e]  += __shfl_xor(sq1[e],  16); sq1[e]  += __shfl_xor(sq1[e],  32);
            #pragma unroll
            for (int h = 0; h < NH; ++h) {
                A0[e][h] += __shfl_xor(A0[e][h], 16);
                A0[e][h] += __shfl_xor(A0[e][h], 32);
                A1[e][h] += __shfl_xor(A1[e][h], 16);
                A1[e][h] += __shfl_xor(A1[e][h], 32);
            }
        }
        if (cg == 0) {
            #pragma unroll
            for (int e = 0; e < 4; ++e) {
                float* pb0 = &pbuf[w][l16 * 4 + e][0];
                pb0[0] = sum0[e];
                pb0[1] = sq0[e];
                #pragma unroll
                for (int h = 0; h < NH; ++h) pb0[2 + h] = A0[e][h];
                float* pb1 = &pbuf[w][64 + l16 * 4 + e][0];
                pb1[0] = sum1[e];
                pb1[1] = sq1[e];
                #pragma unroll
                for (int h = 0; h < NH; ++h) pb1[2 + h] = A1[e][h];
            }
        }
    }
    __syncthreads();

    // ---- combine: 2 waves, thread = s (0..127) ----
    if (tid < 128) {
        int s = tid;
        float sum = 0.f, sq = 0.f;
        float A[NH];
        #pragma unroll
        for (int h = 0; h < NH; ++h) A[h] = 0.f;
        #pragma unroll
        for (int wv = 0; wv < 4; ++wv) {
            const float* pb = &pbuf[wv][s][0];
            sum += pb[0];
            sq  += pb[1];
            #pragma unroll
            for (int h = 0; h < NH; ++h) A[h] += pb[2 + h];
        }
        float mu   = sum * (1.f / C);
        float var  = sq * (1.f / C) - mu * mu;
        float rs   = rsqrtf(var + EPS);
        float murv = mu * rs;

        float l8[NH], z8[NH];
        #pragma unroll
        for (int h = 0; h < NH; ++h) {
            float p = __expf(rs * A[h] - murv * Gv[bn * NH + h] + Bc[bn * NH + h]);
            ptT[h * PTSTR + s] = (unsigned short)(bf_pack(p * rs, 0.f) & 0xffffu);
            l8[h] = p;
            z8[h] = p * murv;
        }
        #pragma unroll
        for (int h = 0; h < NH; ++h) {
            float l = l8[h], zz = z8[h];
            #pragma unroll
            for (int off = 32; off; off >>= 1) {
                l  += __shfl_xor(l,  off);
                zz += __shfl_xor(zz, off);
            }
            if ((tid & 63) == 0) {
                int strip = sg * 2 + (tid >> 6);
                LP[(size_t)(bn * NH + h) * NSTRIP + strip] = l;
                ZP[(size_t)(bn * NH + h) * NSTRIP + strip] = zz;
            }
        }
    }
    __syncthreads();

    // ---- phase 2: MFMA PV (K=128), all operands from LDS ----
    {
        int mrow = lane & 15;     // A row-id bits; D col (= h)
        int kgrp = lane >> 4;     // k block (8 k each)
        float* mp = Mp + (((size_t)sg * 64 + bn) * C) * NH;
        #pragma unroll
        for (int ct = 0; ct < 4; ++ct) {
            int ctile = w * 4 + ct;
            int crow  = ctile * 16 + mrow;
            f32x4 acc = {0.f, 0.f, 0.f, 0.f};
            #pragma unroll
            for (int kc = 0; kc < 4; ++kc) {
                uint4 ap = *reinterpret_cast<const uint4*>(&tile[crow * TSTR + kc * 32 + kgrp * 8]);
                uint4 bp = *reinterpret_cast<const uint4*>(&ptT[mrow * PTSTR + kc * 32 + kgrp * 8]);
                short8 af  = __builtin_bit_cast(short8, ap);
                short8 bfv = __builtin_bit_cast(short8, bp);
                acc = __builtin_amdgcn_mfma_f32_16x16x32_bf16(af, bfv, acc, 0, 0, 0);
            }
            if (mrow < NH) {
                #pragma unroll
                for (int r = 0; r < 4; ++r) {
                    int cl = ctile * 16 + kgrp * 4 + r;
                    mp[cl * NH + mrow] = acc[r];
                }
            }
        }
    }
}

// ---------------------------------------------------------------------------
// KFOLDM: grid 512 = 64 bn x 8 c-slices(32). Thread = (c_local, h).
// Per sg iteration the block reads 1 KB CONTIGUOUS of Mp (coalesced);
// 32 iterations, unroll 8. Applies IL/z/ln_p -> wei.
// ---------------------------------------------------------------------------
__global__ __launch_bounds__(256) void kfoldM(
    const float* __restrict__ Mp, const float* __restrict__ LP, const float* __restrict__ ZP,
    const float* __restrict__ lpw, const float* __restrict__ lpb, float* __restrict__ weig)
{
    int blk = blockIdx.x;
    int bn = blk >> 3, slice = blk & 7;
    int tid = threadIdx.x;
    __shared__ float ilz[2 * NH];

    if (tid < NH) {
        float L = 0.f, Z = 0.f;
        #pragma unroll 8
        for (int j = 0; j < NSTRIP; ++j) {
            L += LP[(size_t)(bn * NH + tid) * NSTRIP + j];
            Z += ZP[(size_t)(bn * NH + tid) * NSTRIP + j];
        }
        float inv = 1.f / L;
        ilz[tid]      = inv;
        ilz[NH + tid] = Z * inv;
    }
    __syncthreads();

    int c0 = slice * 32;
    const float* base = Mp + ((size_t)bn * C + c0) * NH + tid;
    float acc = 0.f;
    #pragma unroll 8
    for (int sg = 0; sg < NSGM; ++sg)
        acc += base[(size_t)sg * 64 * C * NH];

    int c = c0 + (tid >> 3), h = tid & 7;
    weig[(size_t)bn * NH * C + h * C + c] = lpw[c] * (acc * ilz[h] - ilz[NH + h]) + lpb[c];
}

// ---------------------------------------------------------------------------
// KPOST: per bn: wei (global, 2 KB) -> ctx -> Wo -> residual -> MLP -> out.
// Per-thread serial-K GEMVs (L2-hot weight rows, ILP loads).
// ---------------------------------------------------------------------------
__global__ __launch_bounds__(256) void kpost(
    const float* __restrict__ mt, const float* __restrict__ weig,
    const float* __restrict__ Wv, const float* __restrict__ bv,
    const float* __restrict__ Wo, const float* __restrict__ bo,
    const float* __restrict__ W1, const float* __restrict__ b1,
    const float* __restrict__ W2, const float* __restrict__ b2,
    float* __restrict__ out)
{
    int bn  = blockIdx.x;
    int tid = threadIdx.x;
    __shared__ float wei[NH * C];   // [h][c]
    __shared__ float ctxs[C];
    __shared__ float upds[C];
    __shared__ float hid[2 * C];

    for (int v = tid; v < 512; v += 256)
        *reinterpret_cast<float4*>(&wei[v * 4]) =
            *reinterpret_cast<const float4*>(weig + (size_t)bn * NH * C + v * 4);
    __syncthreads();

    {   // ctx[j=tid] = wei[h(j),:] . Wv[j,:] + bv[j]
        int h = tid >> 5;
        float a = bv[tid];
        const float* wrow = Wv + (size_t)tid * C;
        const float* wh   = wei + h * C;
        #pragma unroll 16
        for (int c2 = 0; c2 < C; ++c2) a += wh[c2] * wrow[c2];
        ctxs[tid] = a;
    }
    __syncthreads();

    float att = bo[tid];
    {
        const float* wrow = Wo + (size_t)tid * C;
        #pragma unroll 16
        for (int j = 0; j < C; ++j) att += ctxs[j] * wrow[j];
    }
    float upd = mt[(size_t)bn * C + tid] + att;
    upds[tid] = upd;
    __syncthreads();

    #pragma unroll
    for (int r = 0; r < 2; ++r) {
        int k = tid + r * 256;
        float a = b1[k];
        const float* wrow = W1 + (size_t)k * C;
        #pragma unroll 16
        for (int c2 = 0; c2 < C; ++c2) a += upds[c2] * wrow[c2];
        hid[k] = fmaxf(a, 0.f);
    }
    __syncthreads();

    float a = b2[tid];
    const float* wrow = W2 + (size_t)tid * 2 * C;
    #pragma unroll 16
    for (int k = 0; k < 2 * C; ++k) a += hid[k] * wrow[k];
    out[(size_t)bn * C + tid] = upd + a;
}

extern "C" void kernel_launch(void* const* d_in, const int* in_sizes, int n_in,
                              void* d_out, int out_size, void* d_ws, size_t ws_size,
                              hipStream_t stream)
{
    const float* mt  = (const float*)d_in[0];
    const float* pe  = (const float*)d_in[1];
    const float* ltw = (const float*)d_in[2];
    const float* ltb = (const float*)d_in[3];
    const float* lpw = (const float*)d_in[4];
    const float* lpb = (const float*)d_in[5];
    const float* Wq  = (const float*)d_in[6];
    const float* bq  = (const float*)d_in[7];
    const float* Wk  = (const float*)d_in[8];
    const float* bk  = (const float*)d_in[9];
    const float* Wv  = (const float*)d_in[10];
    const float* bv  = (const float*)d_in[11];
    const float* Wo  = (const float*)d_in[12];
    const float* bo  = (const float*)d_in[13];
    const float* W1  = (const float*)d_in[14];
    const float* b1  = (const float*)d_in[15];
    const float* W2  = (const float*)d_in[16];
    const float* b2  = (const float*)d_in[17];

    float* ws   = (float*)d_ws;
    float* outp = (float*)d_out;

    unsigned int* gwp = (unsigned int*)(ws + OFF_GWP);
    float* Gv         = ws + OFF_G;
    float* Bc         = ws + OFF_BC;
    float* LP         = ws + OFF_LP;
    float* ZP         = ws + OFF_ZP;
    float* weig       = ws + OFF_WEI;
    float* Mp         = ws + OFF_MP;

    k1_prep<<<64,   256, 0, stream>>>(mt, ltw, ltb, lpw, lpb, Wq, bq, Wk, bk, gwp, Gv, Bc);
    kfused <<<2048, 256, 0, stream>>>(pe, gwp, Gv, Bc, LP, ZP, Mp);
    kfoldM <<<512,  256, 0, stream>>>(Mp, LP, ZP, lpw, lpb, weig);
    kpost  <<<64,   256, 0, stream>>>(mt, weig, Wv, bv, Wo, bo, W1, b1, W2, b2, outp);
}

// Round 19
// 136.170 us; speedup vs baseline: 1.3128x; 1.3128x over previous
//
#include <hip/hip_runtime.h>
#include <math.h>

#define C 256
#define S 4096
#define NH 8
#define NSG 64        // 64-s groups per bn = Mp partial groups & LP/ZP strips
#define EPS 1e-5f
#define SCALE 0.17677669529663687f   // 1/sqrt(32)

#define TSTR 72       // tile row stride (u16): 144B rows, 16B-aligned, 2-way banks
#define PTSTR 72      // ptT row stride (u16)

// workspace layout (float offsets)
#define OFF_GWP 0                  // 64*256*4 uints = 65536
#define OFF_G   65536              // 512
#define OFF_BC  66048              // 512
#define OFF_LP  66560              // 64*8*64 = 32768
#define OFF_ZP  99328              // 32768
#define OFF_WEI 132096             // 64*8*256 = 131072
#define OFF_MP  263168             // 64*64*256*8 = 8388608

typedef __attribute__((ext_vector_type(8))) short short8;
typedef __attribute__((ext_vector_type(4))) float f32x4;
typedef __attribute__((ext_vector_type(4))) float nfloat4;   // native clang vector (nt-load ok)

__device__ __forceinline__ float bf_lo(unsigned int u) {
    return __builtin_bit_cast(float, u << 16);
}
__device__ __forceinline__ float bf_hi(unsigned int u) {
    return __builtin_bit_cast(float, u & 0xffff0000u);
}
__device__ __forceinline__ unsigned int bf_pack(float a, float b) {
    unsigned int ua = (__builtin_bit_cast(unsigned int, a) + 0x8000u) >> 16;
    unsigned int ub = (__builtin_bit_cast(unsigned int, b) + 0x8000u) & 0xffff0000u;
    return ua | ub;
}
__device__ __forceinline__ float bf_round(float a) {
    unsigned int u = (__builtin_bit_cast(unsigned int, a) + 0x8000u) & 0xffff0000u;
    return __builtin_bit_cast(float, u);
}

// ---------------------------------------------------------------------------
// K1: LN(mask_tokens) -> q -> fold q into Wk. gw packed bf16 pairs [bn][c][4u].
// ---------------------------------------------------------------------------
__global__ __launch_bounds__(256) void k1_prep(
    const float* __restrict__ mt, const float* __restrict__ ln_t_w, const float* __restrict__ ln_t_b,
    const float* __restrict__ ln_p_w, const float* __restrict__ ln_p_b,
    const float* __restrict__ Wq, const float* __restrict__ bq,
    const float* __restrict__ Wk, const float* __restrict__ bk,
    unsigned int* __restrict__ gwp, float* __restrict__ Gv, float* __restrict__ Bc)
{
    int bn  = blockIdx.x;
    int tid = threadIdx.x;
    int wid = tid >> 6, lane = tid & 63;
    __shared__ float nt[C];
    __shared__ float qv[C];
    __shared__ float wks[NH][C];
    __shared__ float red[8];

    float x  = mt[bn * C + tid];
    float s1 = x, s2 = x * x;
    #pragma unroll
    for (int off = 32; off; off >>= 1) {
        s1 += __shfl_xor(s1, off);
        s2 += __shfl_xor(s2, off);
    }
    if (lane == 0) { red[wid] = s1; red[4 + wid] = s2; }
    __syncthreads();
    float mu   = (red[0] + red[1] + red[2] + red[3]) * (1.0f / C);
    float msq  = (red[4] + red[5] + red[6] + red[7]) * (1.0f / C);
    float rstd = rsqrtf(msq - mu * mu + EPS);
    nt[tid] = (x - mu) * rstd * ln_t_w[tid] + ln_t_b[tid];
    __syncthreads();

    {   // q[j=tid] = nt . Wq[j,:] + bq[j]
        float acc = bq[tid];
        const float* wrow = Wq + (size_t)tid * C;
        #pragma unroll 8
        for (int c = 0; c < C; ++c) acc += nt[c] * wrow[c];
        qv[tid] = acc;
    }
    __syncthreads();

    int c = tid;
    #pragma unroll
    for (int h = 0; h < NH; ++h) {
        float a = 0.f;
        #pragma unroll 4
        for (int d = 0; d < 32; ++d) a += qv[h * 32 + d] * Wk[(size_t)(h * 32 + d) * C + c];
        wks[h][c] = a * SCALE;
    }
    __syncthreads();

    for (int i = tid; i < C * 4; i += 256) {
        int cc = i >> 2, pr = i & 3;
        float g0 = ln_p_w[cc] * wks[pr * 2][cc];
        float g1 = ln_p_w[cc] * wks[pr * 2 + 1][cc];
        gwp[(size_t)bn * C * 4 + i] = bf_pack(g0, g1);
    }

    {
        int h = tid >> 5, l32 = tid & 31;
        float g = 0.f, bs = 0.f;
        #pragma unroll
        for (int cc = l32; cc < C; cc += 32) {
            float w = wks[h][cc];
            g  += bf_round(ln_p_w[cc] * w);   // match kfused's unpacked value
            bs += ln_p_b[cc] * w;
        }
        float qb = qv[h * 32 + l32] * bk[h * 32 + l32];
        #pragma unroll
        for (int off = 16; off; off >>= 1) {
            g  += __shfl_xor(g, off);
            bs += __shfl_xor(bs, off);
            qb += __shfl_xor(qb, off);
        }
        if (l32 == 0) {
            Gv[bn * NH + h] = g;
            Bc[bn * NH + h] = bs + qb * SCALE;
        }
    }
}

// ---------------------------------------------------------------------------
// KFUSED v6.1 (single-touch + nontemporal): grid 4096 = 64 bn x 64 sg(64 s);
// 4 waves; 3 blk/CU. pe loads + Mp stores NONTEMPORAL (both single-touch).
// Phase1: (w,cg,l16) loads 16 float4, packs bf16 tile + stats partials;
// cg-combine shfl_xor(16,32); pbuf cross-wave. Combine (wave0): stats -> p
// (m=0 softmax) -> ptT + LP/ZP. Phase2: MFMA PV from LDS -> Mp direct.
// ---------------------------------------------------------------------------
__global__ __launch_bounds__(256, 3) void kfused(
    const float* __restrict__ pe, const unsigned int* __restrict__ gwp,
    const float* __restrict__ Gv, const float* __restrict__ Bc,
    float* __restrict__ LP, float* __restrict__ ZP, float* __restrict__ Mp)
{
    int blk = blockIdx.x;                     // 4096
    int swz = (blk & 7) * 512 + (blk >> 3);   // XCD-contiguous chunks
    int bn  = swz >> 6;
    int sg  = swz & 63;
    int tid = threadIdx.x;
    int w = tid >> 6, lane = tid & 63;
    int cg = lane >> 4, l16 = lane & 15;
    int b = bn >> 3, n = bn & 7;
    const float* xb = pe + ((size_t)(n * 8 + b)) * C * S;
    int s0 = sg * 64;

    __shared__ unsigned short tile[C * TSTR];   // 36864 B  [c][s] bf16
    __shared__ unsigned short ptT[16 * PTSTR];  // 2304 B   [h][s] bf16 (rows 8-15 zero)
    __shared__ float pbuf[4][64][10];           // 10240 B
    __shared__ uint4 gwt[C];                    // 4096 B

    {
        const uint4* src = reinterpret_cast<const uint4*>(gwp + (size_t)bn * C * 4);
        gwt[tid] = src[tid];
        for (int i = tid; i < 8 * PTSTR; i += 256) ptT[8 * PTSTR + i] = 0;
    }
    __syncthreads();

    // ---- phase 1 ----
    {
        const float* xq = xb + (size_t)(w * 64 + cg) * S + s0 + l16 * 4;
        nfloat4 xr[16];
        #pragma unroll
        for (int j = 0; j < 16; ++j)
            xr[j] = __builtin_nontemporal_load(
                        reinterpret_cast<const nfloat4*>(xq + (size_t)(4 * j) * S));

        float sum[4] = {0.f,0.f,0.f,0.f}, sq[4] = {0.f,0.f,0.f,0.f};
        float A[4][NH];
        #pragma unroll
        for (int e = 0; e < 4; ++e)
            #pragma unroll
            for (int h = 0; h < NH; ++h) A[e][h] = 0.f;

        #pragma unroll
        for (int j = 0; j < 16; ++j) {
            int c = w * 64 + 4 * j + cg;
            uint2 pk;
            pk.x = bf_pack(xr[j].x, xr[j].y);
            pk.y = bf_pack(xr[j].z, xr[j].w);
            *reinterpret_cast<uint2*>(&tile[c * TSTR + l16 * 4]) = pk;
            uint4 g = gwt[c];
            float xe[4] = {xr[j].x, xr[j].y, xr[j].z, xr[j].w};
            #pragma unroll
            for (int e = 0; e < 4; ++e) {
                float xx = xe[e];
                sum[e] += xx;
                sq[e]  += xx * xx;
                A[e][0] += bf_lo(g.x) * xx; A[e][1] += bf_hi(g.x) * xx;
                A[e][2] += bf_lo(g.y) * xx; A[e][3] += bf_hi(g.y) * xx;
                A[e][4] += bf_lo(g.z) * xx; A[e][5] += bf_hi(g.z) * xx;
                A[e][6] += bf_lo(g.w) * xx; A[e][7] += bf_hi(g.w) * xx;
            }
        }
        // cg-combine (lanes sharing l16 across cg hold disjoint c-subsets)
        #pragma unroll
        for (int e = 0; e < 4; ++e) {
            sum[e] += __shfl_xor(sum[e], 16); sum[e] += __shfl_xor(sum[e], 32);
            sq[e]  += __shfl_xor(sq[e],  16); sq[e]  += __shfl_xor(sq[e],  32);
            #pragma unroll
            for (int h = 0; h < NH; ++h) {
                A[e][h] += __shfl_xor(A[e][h], 16);
                A[e][h] += __shfl_xor(A[e][h], 32);
            }
        }
        if (cg == 0) {
            #pragma unroll
            for (int e = 0; e < 4; ++e) {
                float* pb = &pbuf[w][l16 * 4 + e][0];
                pb[0] = sum[e];
                pb[1] = sq[e];
                #pragma unroll
                for (int h = 0; h < NH; ++h) pb[2 + h] = A[e][h];
            }
        }
    }
    __syncthreads();

    // ---- combine: wave 0, thread = s ----
    if (tid < 64) {
        int s = tid;
        float sum = 0.f, sq = 0.f;
        float A[NH];
        #pragma unroll
        for (int h = 0; h < NH; ++h) A[h] = 0.f;
        #pragma unroll
        for (int wv = 0; wv < 4; ++wv) {
            const float* pb = &pbuf[wv][s][0];
            sum += pb[0];
            sq  += pb[1];
            #pragma unroll
            for (int h = 0; h < NH; ++h) A[h] += pb[2 + h];
        }
        float mu   = sum * (1.f / C);
        float var  = sq * (1.f / C) - mu * mu;
        float rs   = rsqrtf(var + EPS);
        float murv = mu * rs;

        float l8[NH], z8[NH];
        #pragma unroll
        for (int h = 0; h < NH; ++h) {
            float p = __expf(rs * A[h] - murv * Gv[bn * NH + h] + Bc[bn * NH + h]);
            ptT[h * PTSTR + s] = (unsigned short)(bf_pack(p * rs, 0.f) & 0xffffu);
            l8[h] = p;
            z8[h] = p * murv;
        }
        #pragma unroll
        for (int h = 0; h < NH; ++h) {
            float l = l8[h], zz = z8[h];
            #pragma unroll
            for (int off = 32; off; off >>= 1) {
                l  += __shfl_xor(l,  off);
                zz += __shfl_xor(zz, off);
            }
            if (tid == 0) {
                LP[(size_t)(bn * NH + h) * NSG + sg] = l;
                ZP[(size_t)(bn * NH + h) * NSG + sg] = zz;
            }
        }
    }
    __syncthreads();

    // ---- phase 2: MFMA PV, all operands from LDS; nt stores to Mp ----
    {
        int mrow = lane & 15;     // A row-id bits; D col (= h)
        int kgrp = lane >> 4;     // k block (8 k each)
        float* mp = Mp + (((size_t)sg * 64 + bn) * C) * NH;
        #pragma unroll
        for (int ct = 0; ct < 4; ++ct) {
            int ctile = w * 4 + ct;
            int crow  = ctile * 16 + mrow;
            f32x4 acc = {0.f, 0.f, 0.f, 0.f};
            #pragma unroll
            for (int kc = 0; kc < 2; ++kc) {
                uint4 ap = *reinterpret_cast<const uint4*>(&tile[crow * TSTR + kc * 32 + kgrp * 8]);
                uint4 bp = *reinterpret_cast<const uint4*>(&ptT[mrow * PTSTR + kc * 32 + kgrp * 8]);
                short8 af  = __builtin_bit_cast(short8, ap);
                short8 bfv = __builtin_bit_cast(short8, bp);
                acc = __builtin_amdgcn_mfma_f32_16x16x32_bf16(af, bfv, acc, 0, 0, 0);
            }
            if (mrow < NH) {
                #pragma unroll
                for (int r = 0; r < 4; ++r) {
                    int cl = ctile * 16 + kgrp * 4 + r;
                    __builtin_nontemporal_store(acc[r], mp + cl * NH + mrow);
                }
            }
        }
    }
}

// ---------------------------------------------------------------------------
// KFOLDM: grid 512 = 64 bn x 8 c-slices(32). Thread = (c_local, h).
// Per sg iteration the block reads 1 KB CONTIGUOUS of Mp (coalesced, nt);
// 64 iterations, unroll 8 (8 loads in flight). Applies IL/z/ln_p -> wei.
// ---------------------------------------------------------------------------
__global__ __launch_bounds__(256) void kfoldM(
    const float* __restrict__ Mp, const float* __restrict__ LP, const float* __restrict__ ZP,
    const float* __restrict__ lpw, const float* __restrict__ lpb, float* __restrict__ weig)
{
    int blk = blockIdx.x;
    int bn = blk >> 3, slice = blk & 7;
    int tid = threadIdx.x;
    __shared__ float ilz[2 * NH];

    if (tid < NH) {
        float L = 0.f, Z = 0.f;
        #pragma unroll 8
        for (int j = 0; j < NSG; ++j) {
            L += LP[(size_t)(bn * NH + tid) * NSG + j];
            Z += ZP[(size_t)(bn * NH + tid) * NSG + j];
        }
        float inv = 1.f / L;
        ilz[tid]      = inv;
        ilz[NH + tid] = Z * inv;
    }
    __syncthreads();

    int c0 = slice * 32;
    const float* base = Mp + ((size_t)bn * C + c0) * NH + tid;
    float acc = 0.f;
    #pragma unroll 8
    for (int sg = 0; sg < NSG; ++sg)
        acc += __builtin_nontemporal_load(base + (size_t)sg * 64 * C * NH);

    int c = c0 + (tid >> 3), h = tid & 7;
    weig[(size_t)bn * NH * C + h * C + c] = lpw[c] * (acc * ilz[h] - ilz[NH + h]) + lpb[c];
}

// ---------------------------------------------------------------------------
// KPOST: per bn: wei (global, 2 KB) -> ctx -> Wo -> residual -> MLP -> out.
// Per-thread serial-K GEMVs (L2-hot weight rows, ILP loads).
// ---------------------------------------------------------------------------
__global__ __launch_bounds__(256) void kpost(
    const float* __restrict__ mt, const float* __restrict__ weig,
    const float* __restrict__ Wv, const float* __restrict__ bv,
    const float* __restrict__ Wo, const float* __restrict__ bo,
    const float* __restrict__ W1, const float* __restrict__ b1,
    const float* __restrict__ W2, const float* __restrict__ b2,
    float* __restrict__ out)
{
    int bn  = blockIdx.x;
    int tid = threadIdx.x;
    __shared__ float wei[NH * C];   // [h][c]
    __shared__ float ctxs[C];
    __shared__ float upds[C];
    __shared__ float hid[2 * C];

    for (int v = tid; v < 512; v += 256)
        *reinterpret_cast<float4*>(&wei[v * 4]) =
            *reinterpret_cast<const float4*>(weig + (size_t)bn * NH * C + v * 4);
    __syncthreads();

    {   // ctx[j=tid] = wei[h(j),:] . Wv[j,:] + bv[j]
        int h = tid >> 5;
        float a = bv[tid];
        const float* wrow = Wv + (size_t)tid * C;
        const float* wh   = wei + h * C;
        #pragma unroll 16
        for (int c2 = 0; c2 < C; ++c2) a += wh[c2] * wrow[c2];
        ctxs[tid] = a;
    }
    __syncthreads();

    float att = bo[tid];
    {
        const float* wrow = Wo + (size_t)tid * C;
        #pragma unroll 16
        for (int j = 0; j < C; ++j) att += ctxs[j] * wrow[j];
    }
    float upd = mt[(size_t)bn * C + tid] + att;
    upds[tid] = upd;
    __syncthreads();

    #pragma unroll
    for (int r = 0; r < 2; ++r) {
        int k = tid + r * 256;
        float a = b1[k];
        const float* wrow = W1 + (size_t)k * C;
        #pragma unroll 16
        for (int c2 = 0; c2 < C; ++c2) a += upds[c2] * wrow[c2];
        hid[k] = fmaxf(a, 0.f);
    }
    __syncthreads();

    float a = b2[tid];
    const float* wrow = W2 + (size_t)tid * 2 * C;
    #pragma unroll 16
    for (int k = 0; k < 2 * C; ++k) a += hid[k] * wrow[k];
    out[(size_t)bn * C + tid] = upd + a;
}

extern "C" void kernel_launch(void* const* d_in, const int* in_sizes, int n_in,
                              void* d_out, int out_size, void* d_ws, size_t ws_size,
                              hipStream_t stream)
{
    const float* mt  = (const float*)d_in[0];
    const float* pe  = (const float*)d_in[1];
    const float* ltw = (const float*)d_in[2];
    const float* ltb = (const float*)d_in[3];
    const float* lpw = (const float*)d_in[4];
    const float* lpb = (const float*)d_in[5];
    const float* Wq  = (const float*)d_in[6];
    const float* bq  = (const float*)d_in[7];
    const float* Wk  = (const float*)d_in[8];
    const float* bk  = (const float*)d_in[9];
    const float* Wv  = (const float*)d_in[10];
    const float* bv  = (const float*)d_in[11];
    const float* Wo  = (const float*)d_in[12];
    const float* bo  = (const float*)d_in[13];
    const float* W1  = (const float*)d_in[14];
    const float* b1  = (const float*)d_in[15];
    const float* W2  = (const float*)d_in[16];
    const float* b2  = (const float*)d_in[17];

    float* ws   = (float*)d_ws;
    float* outp = (float*)d_out;

    unsigned int* gwp = (unsigned int*)(ws + OFF_GWP);
    float* Gv         = ws + OFF_G;
    float* Bc         = ws + OFF_BC;
    float* LP         = ws + OFF_LP;
    float* ZP         = ws + OFF_ZP;
    float* weig       = ws + OFF_WEI;
    float* Mp         = ws + OFF_MP;

    k1_prep<<<64,   256, 0, stream>>>(mt, ltw, ltb, lpw, lpb, Wq, bq, Wk, bk, gwp, Gv, Bc);
    kfused <<<4096, 256, 0, stream>>>(pe, gwp, Gv, Bc, LP, ZP, Mp);
    kfoldM <<<512,  256, 0, stream>>>(Mp, LP, ZP, lpw, lpb, weig);
    kpost  <<<64,   256, 0, stream>>>(mt, weig, Wv, bv, Wo, bo, W1, b1, W2, b2, outp);
}

// Round 20
// 132.914 us; speedup vs baseline: 1.3449x; 1.0245x over previous
//
#include <hip/hip_runtime.h>
#include <math.h>

#define C 256
#define S 4096
#define NH 8
#define NSG 64        // 64-s groups per bn = Mp partial groups & LP/ZP strips
#define EPS 1e-5f
#define SCALE 0.17677669529663687f   // 1/sqrt(32)

#define TSTR 72       // tile row stride (u16): 144B rows, 16B-aligned, 2-way banks
#define PTSTR 72      // ptT row stride (u16)

// workspace layout (float offsets)
#define OFF_GWP 0                  // 64*256*4 uints = 65536
#define OFF_G   65536              // 512
#define OFF_BC  66048              // 512
#define OFF_LP  66560              // 64*8*64 = 32768
#define OFF_ZP  99328              // 32768
#define OFF_WEI 132096             // 64*8*256 = 131072
#define OFF_MP  263168             // bf16: 64*64*8*256*2B = 16 MB -> 4194304 floats

typedef __attribute__((ext_vector_type(8))) short short8;
typedef __attribute__((ext_vector_type(4))) float f32x4;
typedef __attribute__((ext_vector_type(4))) float nfloat4;   // native clang vector (nt-load ok)

__device__ __forceinline__ float bf_lo(unsigned int u) {
    return __builtin_bit_cast(float, u << 16);
}
__device__ __forceinline__ float bf_hi(unsigned int u) {
    return __builtin_bit_cast(float, u & 0xffff0000u);
}
__device__ __forceinline__ unsigned int bf_pack(float a, float b) {
    unsigned int ua = (__builtin_bit_cast(unsigned int, a) + 0x8000u) >> 16;
    unsigned int ub = (__builtin_bit_cast(unsigned int, b) + 0x8000u) & 0xffff0000u;
    return ua | ub;
}
__device__ __forceinline__ float bf_round(float a) {
    unsigned int u = (__builtin_bit_cast(unsigned int, a) + 0x8000u) & 0xffff0000u;
    return __builtin_bit_cast(float, u);
}
__device__ __forceinline__ float bf_us(unsigned short v) {
    return __builtin_bit_cast(float, (unsigned int)v << 16);
}

// ---------------------------------------------------------------------------
// K1: LN(mask_tokens) -> q -> fold q into Wk. gw packed bf16 pairs [bn][c][4u].
// ---------------------------------------------------------------------------
__global__ __launch_bounds__(256) void k1_prep(
    const float* __restrict__ mt, const float* __restrict__ ln_t_w, const float* __restrict__ ln_t_b,
    const float* __restrict__ ln_p_w, const float* __restrict__ ln_p_b,
    const float* __restrict__ Wq, const float* __restrict__ bq,
    const float* __restrict__ Wk, const float* __restrict__ bk,
    unsigned int* __restrict__ gwp, float* __restrict__ Gv, float* __restrict__ Bc)
{
    int bn  = blockIdx.x;
    int tid = threadIdx.x;
    int wid = tid >> 6, lane = tid & 63;
    __shared__ float nt[C];
    __shared__ float qv[C];
    __shared__ float wks[NH][C];
    __shared__ float red[8];

    float x  = mt[bn * C + tid];
    float s1 = x, s2 = x * x;
    #pragma unroll
    for (int off = 32; off; off >>= 1) {
        s1 += __shfl_xor(s1, off);
        s2 += __shfl_xor(s2, off);
    }
    if (lane == 0) { red[wid] = s1; red[4 + wid] = s2; }
    __syncthreads();
    float mu   = (red[0] + red[1] + red[2] + red[3]) * (1.0f / C);
    float msq  = (red[4] + red[5] + red[6] + red[7]) * (1.0f / C);
    float rstd = rsqrtf(msq - mu * mu + EPS);
    nt[tid] = (x - mu) * rstd * ln_t_w[tid] + ln_t_b[tid];
    __syncthreads();

    {   // q[j=tid] = nt . Wq[j,:] + bq[j]
        float acc = bq[tid];
        const float* wrow = Wq + (size_t)tid * C;
        #pragma unroll 8
        for (int c = 0; c < C; ++c) acc += nt[c] * wrow[c];
        qv[tid] = acc;
    }
    __syncthreads();

    int c = tid;
    #pragma unroll
    for (int h = 0; h < NH; ++h) {
        float a = 0.f;
        #pragma unroll 4
        for (int d = 0; d < 32; ++d) a += qv[h * 32 + d] * Wk[(size_t)(h * 32 + d) * C + c];
        wks[h][c] = a * SCALE;
    }
    __syncthreads();

    for (int i = tid; i < C * 4; i += 256) {
        int cc = i >> 2, pr = i & 3;
        float g0 = ln_p_w[cc] * wks[pr * 2][cc];
        float g1 = ln_p_w[cc] * wks[pr * 2 + 1][cc];
        gwp[(size_t)bn * C * 4 + i] = bf_pack(g0, g1);
    }

    {
        int h = tid >> 5, l32 = tid & 31;
        float g = 0.f, bs = 0.f;
        #pragma unroll
        for (int cc = l32; cc < C; cc += 32) {
            float w = wks[h][cc];
            g  += bf_round(ln_p_w[cc] * w);   // match kfused's unpacked value
            bs += ln_p_b[cc] * w;
        }
        float qb = qv[h * 32 + l32] * bk[h * 32 + l32];
        #pragma unroll
        for (int off = 16; off; off >>= 1) {
            g  += __shfl_xor(g, off);
            bs += __shfl_xor(bs, off);
            qb += __shfl_xor(qb, off);
        }
        if (l32 == 0) {
            Gv[bn * NH + h] = g;
            Bc[bn * NH + h] = bs + qb * SCALE;
        }
    }
}

// ---------------------------------------------------------------------------
// KFUSED v6.2 (single-touch + nt + bf16 Mp): grid 4096 = 64 bn x 64 sg(64 s);
// 4 waves; 3 blk/CU. pe loads nt; Mp partials stored bf16 [sg][bn][h][c]
// (nt uint2 per lane: 4 consecutive c for head mrow).
// ---------------------------------------------------------------------------
__global__ __launch_bounds__(256, 3) void kfused(
    const float* __restrict__ pe, const unsigned int* __restrict__ gwp,
    const float* __restrict__ Gv, const float* __restrict__ Bc,
    float* __restrict__ LP, float* __restrict__ ZP, unsigned short* __restrict__ Mp)
{
    int blk = blockIdx.x;                     // 4096
    int swz = (blk & 7) * 512 + (blk >> 3);   // XCD-contiguous chunks
    int bn  = swz >> 6;
    int sg  = swz & 63;
    int tid = threadIdx.x;
    int w = tid >> 6, lane = tid & 63;
    int cg = lane >> 4, l16 = lane & 15;
    int b = bn >> 3, n = bn & 7;
    const float* xb = pe + ((size_t)(n * 8 + b)) * C * S;
    int s0 = sg * 64;

    __shared__ unsigned short tile[C * TSTR];   // 36864 B  [c][s] bf16
    __shared__ unsigned short ptT[16 * PTSTR];  // 2304 B   [h][s] bf16 (rows 8-15 zero)
    __shared__ float pbuf[4][64][10];           // 10240 B
    __shared__ uint4 gwt[C];                    // 4096 B

    {
        const uint4* src = reinterpret_cast<const uint4*>(gwp + (size_t)bn * C * 4);
        gwt[tid] = src[tid];
        for (int i = tid; i < 8 * PTSTR; i += 256) ptT[8 * PTSTR + i] = 0;
    }
    __syncthreads();

    // ---- phase 1 ----
    {
        const float* xq = xb + (size_t)(w * 64 + cg) * S + s0 + l16 * 4;
        nfloat4 xr[16];
        #pragma unroll
        for (int j = 0; j < 16; ++j)
            xr[j] = __builtin_nontemporal_load(
                        reinterpret_cast<const nfloat4*>(xq + (size_t)(4 * j) * S));

        float sum[4] = {0.f,0.f,0.f,0.f}, sq[4] = {0.f,0.f,0.f,0.f};
        float A[4][NH];
        #pragma unroll
        for (int e = 0; e < 4; ++e)
            #pragma unroll
            for (int h = 0; h < NH; ++h) A[e][h] = 0.f;

        #pragma unroll
        for (int j = 0; j < 16; ++j) {
            int c = w * 64 + 4 * j + cg;
            uint2 pk;
            pk.x = bf_pack(xr[j].x, xr[j].y);
            pk.y = bf_pack(xr[j].z, xr[j].w);
            *reinterpret_cast<uint2*>(&tile[c * TSTR + l16 * 4]) = pk;
            uint4 g = gwt[c];
            float xe[4] = {xr[j].x, xr[j].y, xr[j].z, xr[j].w};
            #pragma unroll
            for (int e = 0; e < 4; ++e) {
                float xx = xe[e];
                sum[e] += xx;
                sq[e]  += xx * xx;
                A[e][0] += bf_lo(g.x) * xx; A[e][1] += bf_hi(g.x) * xx;
                A[e][2] += bf_lo(g.y) * xx; A[e][3] += bf_hi(g.y) * xx;
                A[e][4] += bf_lo(g.z) * xx; A[e][5] += bf_hi(g.z) * xx;
                A[e][6] += bf_lo(g.w) * xx; A[e][7] += bf_hi(g.w) * xx;
            }
        }
        // cg-combine (lanes sharing l16 across cg hold disjoint c-subsets)
        #pragma unroll
        for (int e = 0; e < 4; ++e) {
            sum[e] += __shfl_xor(sum[e], 16); sum[e] += __shfl_xor(sum[e], 32);
            sq[e]  += __shfl_xor(sq[e],  16); sq[e]  += __shfl_xor(sq[e],  32);
            #pragma unroll
            for (int h = 0; h < NH; ++h) {
                A[e][h] += __shfl_xor(A[e][h], 16);
                A[e][h] += __shfl_xor(A[e][h], 32);
            }
        }
        if (cg == 0) {
            #pragma unroll
            for (int e = 0; e < 4; ++e) {
                float* pb = &pbuf[w][l16 * 4 + e][0];
                pb[0] = sum[e];
                pb[1] = sq[e];
                #pragma unroll
                for (int h = 0; h < NH; ++h) pb[2 + h] = A[e][h];
            }
        }
    }
    __syncthreads();

    // ---- combine: wave 0, thread = s ----
    if (tid < 64) {
        int s = tid;
        float sum = 0.f, sq = 0.f;
        float A[NH];
        #pragma unroll
        for (int h = 0; h < NH; ++h) A[h] = 0.f;
        #pragma unroll
        for (int wv = 0; wv < 4; ++wv) {
            const float* pb = &pbuf[wv][s][0];
            sum += pb[0];
            sq  += pb[1];
            #pragma unroll
            for (int h = 0; h < NH; ++h) A[h] += pb[2 + h];
        }
        float mu   = sum * (1.f / C);
        float var  = sq * (1.f / C) - mu * mu;
        float rs   = rsqrtf(var + EPS);
        float murv = mu * rs;

        float l8[NH], z8[NH];
        #pragma unroll
        for (int h = 0; h < NH; ++h) {
            float p = __expf(rs * A[h] - murv * Gv[bn * NH + h] + Bc[bn * NH + h]);
            ptT[h * PTSTR + s] = (unsigned short)(bf_pack(p * rs, 0.f) & 0xffffu);
            l8[h] = p;
            z8[h] = p * murv;
        }
        #pragma unroll
        for (int h = 0; h < NH; ++h) {
            float l = l8[h], zz = z8[h];
            #pragma unroll
            for (int off = 32; off; off >>= 1) {
                l  += __shfl_xor(l,  off);
                zz += __shfl_xor(zz, off);
            }
            if (tid == 0) {
                LP[(size_t)(bn * NH + h) * NSG + sg] = l;
                ZP[(size_t)(bn * NH + h) * NSG + sg] = zz;
            }
        }
    }
    __syncthreads();

    // ---- phase 2: MFMA PV from LDS; bf16 nt uint2 stores to Mp[sg][bn][h][c] ----
    {
        int mrow = lane & 15;     // A row-id bits; D col (= h)
        int kgrp = lane >> 4;     // k block (8 k each)
        unsigned short* mp = Mp + (((size_t)sg * 64 + bn) * NH) * C;
        #pragma unroll
        for (int ct = 0; ct < 4; ++ct) {
            int ctile = w * 4 + ct;
            int crow  = ctile * 16 + mrow;
            f32x4 acc = {0.f, 0.f, 0.f, 0.f};
            #pragma unroll
            for (int kc = 0; kc < 2; ++kc) {
                uint4 ap = *reinterpret_cast<const uint4*>(&tile[crow * TSTR + kc * 32 + kgrp * 8]);
                uint4 bp = *reinterpret_cast<const uint4*>(&ptT[mrow * PTSTR + kc * 32 + kgrp * 8]);
                short8 af  = __builtin_bit_cast(short8, ap);
                short8 bfv = __builtin_bit_cast(short8, bp);
                acc = __builtin_amdgcn_mfma_f32_16x16x32_bf16(af, bfv, acc, 0, 0, 0);
            }
            if (mrow < NH) {
                int cbase = ctile * 16 + kgrp * 4;
                unsigned int u0 = bf_pack(acc[0], acc[1]);
                unsigned int u1 = bf_pack(acc[2], acc[3]);
                unsigned int* dst = reinterpret_cast<unsigned int*>(mp + (size_t)mrow * C + cbase);
                __builtin_nontemporal_store(u0, dst);
                __builtin_nontemporal_store(u1, dst + 1);
            }
        }
    }
}

// ---------------------------------------------------------------------------
// KFOLDM v2: grid 512 = 64 bn x 8 h-slices. Thread = c. Per sg the block
// reads 512 B CONTIGUOUS bf16 (row [sg][bn][h][:]) nt; 64 iters unroll 8.
// IL/z from 64 strips via wave reduce. weig[bn][h][c] f32.
// ---------------------------------------------------------------------------
__global__ __launch_bounds__(256) void kfoldM(
    const unsigned short* __restrict__ Mp, const float* __restrict__ LP, const float* __restrict__ ZP,
    const float* __restrict__ lpw, const float* __restrict__ lpb, float* __restrict__ weig)
{
    int blk = blockIdx.x;
    int bn = blk >> 3, h = blk & 7;
    int tid = threadIdx.x;
    __shared__ float ilz[2];

    {   // L,Z over 64 strips: wave 0 reduces
        if (tid < 64) {
            float l = LP[(size_t)(bn * NH + h) * NSG + tid];
            float z = ZP[(size_t)(bn * NH + h) * NSG + tid];
            #pragma unroll
            for (int off = 32; off; off >>= 1) {
                l += __shfl_xor(l, off);
                z += __shfl_xor(z, off);
            }
            if (tid == 0) {
                float inv = 1.f / l;
                ilz[0] = inv;
                ilz[1] = z * inv;
            }
        }
    }
    __syncthreads();

    const unsigned short* base = Mp + ((size_t)bn * NH + h) * C + tid;
    float acc = 0.f;
    #pragma unroll 8
    for (int sg = 0; sg < NSG; ++sg)
        acc += bf_us(__builtin_nontemporal_load(base + (size_t)sg * 64 * NH * C));

    int c = tid;
    weig[(size_t)bn * NH * C + h * C + c] = lpw[c] * (acc * ilz[0] - ilz[1]) + lpb[c];
}

// ---------------------------------------------------------------------------
// KPOST: per bn: wei (global, 2 KB) -> ctx -> Wo -> residual -> MLP -> out.
// Per-thread serial-K GEMVs (L2-hot weight rows, ILP loads).
// ---------------------------------------------------------------------------
__global__ __launch_bounds__(256) void kpost(
    const float* __restrict__ mt, const float* __restrict__ weig,
    const float* __restrict__ Wv, const float* __restrict__ bv,
    const float* __restrict__ Wo, const float* __restrict__ bo,
    const float* __restrict__ W1, const float* __restrict__ b1,
    const float* __restrict__ W2, const float* __restrict__ b2,
    float* __restrict__ out)
{
    int bn  = blockIdx.x;
    int tid = threadIdx.x;
    __shared__ float wei[NH * C];   // [h][c]
    __shared__ float ctxs[C];
    __shared__ float upds[C];
    __shared__ float hid[2 * C];

    for (int v = tid; v < 512; v += 256)
        *reinterpret_cast<float4*>(&wei[v * 4]) =
            *reinterpret_cast<const float4*>(weig + (size_t)bn * NH * C + v * 4);
    __syncthreads();

    {   // ctx[j=tid] = wei[h(j),:] . Wv[j,:] + bv[j]
        int h = tid >> 5;
        float a = bv[tid];
        const float* wrow = Wv + (size_t)tid * C;
        const float* wh   = wei + h * C;
        #pragma unroll 16
        for (int c2 = 0; c2 < C; ++c2) a += wh[c2] * wrow[c2];
        ctxs[tid] = a;
    }
    __syncthreads();

    float att = bo[tid];
    {
        const float* wrow = Wo + (size_t)tid * C;
        #pragma unroll 16
        for (int j = 0; j < C; ++j) att += ctxs[j] * wrow[j];
    }
    float upd = mt[(size_t)bn * C + tid] + att;
    upds[tid] = upd;
    __syncthreads();

    #pragma unroll
    for (int r = 0; r < 2; ++r) {
        int k = tid + r * 256;
        float a = b1[k];
        const float* wrow = W1 + (size_t)k * C;
        #pragma unroll 16
        for (int c2 = 0; c2 < C; ++c2) a += upds[c2] * wrow[c2];
        hid[k] = fmaxf(a, 0.f);
    }
    __syncthreads();

    float a = b2[tid];
    const float* wrow = W2 + (size_t)tid * 2 * C;
    #pragma unroll 16
    for (int k = 0; k < 2 * C; ++k) a += hid[k] * wrow[k];
    out[(size_t)bn * C + tid] = upd + a;
}

extern "C" void kernel_launch(void* const* d_in, const int* in_sizes, int n_in,
                              void* d_out, int out_size, void* d_ws, size_t ws_size,
                              hipStream_t stream)
{
    const float* mt  = (const float*)d_in[0];
    const float* pe  = (const float*)d_in[1];
    const float* ltw = (const float*)d_in[2];
    const float* ltb = (const float*)d_in[3];
    const float* lpw = (const float*)d_in[4];
    const float* lpb = (const float*)d_in[5];
    const float* Wq  = (const float*)d_in[6];
    const float* bq  = (const float*)d_in[7];
    const float* Wk  = (const float*)d_in[8];
    const float* bk  = (const float*)d_in[9];
    const float* Wv  = (const float*)d_in[10];
    const float* bv  = (const float*)d_in[11];
    const float* Wo  = (const float*)d_in[12];
    const float* bo  = (const float*)d_in[13];
    const float* W1  = (const float*)d_in[14];
    const float* b1  = (const float*)d_in[15];
    const float* W2  = (const float*)d_in[16];
    const float* b2  = (const float*)d_in[17];

    float* ws   = (float*)d_ws;
    float* outp = (float*)d_out;

    unsigned int* gwp   = (unsigned int*)(ws + OFF_GWP);
    float* Gv           = ws + OFF_G;
    float* Bc           = ws + OFF_BC;
    float* LP           = ws + OFF_LP;
    float* ZP           = ws + OFF_ZP;
    float* weig         = ws + OFF_WEI;
    unsigned short* Mp  = (unsigned short*)(ws + OFF_MP);

    k1_prep<<<64,   256, 0, stream>>>(mt, ltw, ltb, lpw, lpb, Wq, bq, Wk, bk, gwp, Gv, Bc);
    kfused <<<4096, 256, 0, stream>>>(pe, gwp, Gv, Bc, LP, ZP, Mp);
    kfoldM <<<512,  256, 0, stream>>>(Mp, LP, ZP, lpw, lpb, weig);
    kpost  <<<64,   256, 0, stream>>>(mt, weig, Wv, bv, Wo, bo, W1, b1, W2, b2, outp);
}